// Round 8
// baseline (835.268 us; speedup 1.0000x reference)
//
#include <hip/hip_runtime.h>

// LSTM T=2048,B=2048,H=32,I=1,O=1 fused in ONE kernel.
// R8: one wave64 per batch element, TWO adjacent lanes per hidden unit
// (lane 2j: k in [0,16); lane 2j+1: k in [16,32)). 2048 waves = 2 waves/SIMD
// so one wave's dependency stalls (LDS round-trip, trans chains) are filled
// by the other's issue -- R7 was issue-bound at 1 wave/SIMD with 35% bubbles.
// All cross-lane traffic stays inside quads -> DPP quad_perm[1,0,3,2]
// (pure VALU): k-half combine (4 dpp_add), transcendental split across the
// pair (even lane: sigmoid(i),sigmoid(f); odd: tanh(g),sigmoid(o) -> 6 trans
// per lane instead of 10) exchanged back by 2 dpp movs + cndmasks.
// f32 throughout (f16 failed accuracy in R6). Activation exp2 scales baked
// into weights/biases. O=1 projection via DPP + readlane (no DS waits).

namespace {
constexpr int T_ = 2048;
constexpr int B_ = 2048;
constexpr int H_ = 32;
constexpr int EPB = 4;              // elements (= waves) per block
constexpr int CHUNK = 64;           // timesteps of x held in one VGPR
constexpr int NCH = T_ / CHUNK;     // 32
constexpr int OUTS = T_ * B_;       // floats of outs [T,B,1]
constexpr float L2E = 1.442695040888963f;  // log2(e)

typedef float v2f __attribute__((ext_vector_type(2)));
typedef float v4f __attribute__((ext_vector_type(4)));

__device__ __forceinline__ float rcp_(float v){ return __builtin_amdgcn_rcpf(v); }
__device__ __forceinline__ float ex2_(float v){ return __builtin_amdgcn_exp2f(v); }

template <int CTRL, int RM, int BM, bool BC>
__device__ __forceinline__ float dpp_movf(float src) {
    return __builtin_bit_cast(float,
        __builtin_amdgcn_update_dpp(0, __builtin_bit_cast(int, src),
                                    CTRL, RM, BM, BC));
}
template <int CTRL, int RM, int BM, bool BC>
__device__ __forceinline__ float dpp_add(float acc, float src) {
    return acc + dpp_movf<CTRL,RM,BM,BC>(src);
}
} // namespace

__global__ __launch_bounds__(256, 2) void lstm_fused8(
    const float* __restrict__ x,      // [T,B,1]
    const float* __restrict__ W_ih,   // [4H,1]
    const float* __restrict__ W_hh,   // [4H,H]
    const float* __restrict__ b_ih,   // [4H]
    const float* __restrict__ b_hh,   // [4H]
    const float* __restrict__ W_out,  // [1,H]
    const float* __restrict__ b_out,  // [1]
    float* __restrict__ out)          // outs | hT | cT
{
    const int l  = threadIdx.x & 63;
    const int wv = threadIdx.x >> 6;
    const int j  = l >> 1;            // hidden unit (2 lanes per unit)
    const int kh = l & 1;             // k-half: [kh*16, kh*16+16)
    const int e  = blockIdx.x * EPB + wv;
    const bool odd = (kh != 0);

    __shared__ __align__(16) float hbuf[EPB][H_];

    const float sI = -L2E, sF = -L2E, sG = 2.0f*L2E, sO = -L2E;

    // Per-lane recurrent weights: 4 gates x 16 k (this lane's k-range),
    // pre-scaled so activations need no dependent mul before exp2.
    v2f wI[8], wF[8], wG[8], wO[8];
#pragma unroll
    for (int q = 0; q < 8; ++q) {
        const int k = kh*16 + 2*q;
        wI[q] = (v2f){ W_hh[(0*H_+j)*H_+k]*sI, W_hh[(0*H_+j)*H_+k+1]*sI };
        wF[q] = (v2f){ W_hh[(1*H_+j)*H_+k]*sF, W_hh[(1*H_+j)*H_+k+1]*sF };
        wG[q] = (v2f){ W_hh[(2*H_+j)*H_+k]*sG, W_hh[(2*H_+j)*H_+k+1]*sG };
        wO[q] = (v2f){ W_hh[(3*H_+j)*H_+k]*sO, W_hh[(3*H_+j)*H_+k+1]*sO };
    }

    const float wxI = W_ih[0*H_+j]*sI, wxF = W_ih[1*H_+j]*sF;
    const float wxG = W_ih[2*H_+j]*sG, wxO = W_ih[3*H_+j]*sO;
    const float bI = (b_ih[0*H_+j]+b_hh[0*H_+j])*sI;
    const float bF = (b_ih[1*H_+j]+b_hh[1*H_+j])*sF;
    const float bG = (b_ih[2*H_+j]+b_hh[2*H_+j])*sG;
    const float bO = (b_ih[3*H_+j]+b_hh[3*H_+j])*sO;
    // P-gate activation constants: even lane sigmoid(i), odd lane tanh(g)
    const float cP0 = odd ? 1.0f : 0.0f;
    const float cP1 = odd ? -2.0f : 1.0f;
    const float woutM = odd ? 0.0f : W_out[j];   // mask odd lanes in proj
    const float bout  = b_out[0];

    float c = 0.0f, h = 0.0f;
    hbuf[wv][j] = 0.0f;               // h0 = 0 (pair writes same value: ok)
    __asm__ __volatile__("" ::: "memory");
    const float* hp = &hbuf[wv][kh*16];
    v4f h4[4];
#pragma unroll
    for (int q = 0; q < 4; ++q) h4[q] = ((const v4f*)hp)[q];

    float xcur = x[l * B_ + e];       // chunk 0: lane l holds t=l
    int outOff = e;                   // running offset: out[t*B_ + e]

    for (int ch = 0; ch < NCH; ++ch) {
        // keep weights VGPR-class across the inner loop
#pragma unroll
        for (int q = 0; q < 8; ++q) {
            __asm__ __volatile__("" : "+v"(wI[q]), "+v"(wF[q]));
            __asm__ __volatile__("" : "+v"(wG[q]), "+v"(wO[q]));
        }
        float xnext = 0.0f;
        if (ch + 1 < NCH) xnext = x[((ch+1)*CHUNK + l) * B_ + e];
#pragma unroll 8
        for (int s = 0; s < CHUNK; ++s) {
            // x broadcast (uniform, off the h-chain)
            const float xk = __builtin_bit_cast(float,
                __builtin_amdgcn_readlane(__builtin_bit_cast(int, xcur), s));
            const float xtI = bI + xk*wxI;
            const float xtF = bF + xk*wxF;
            const float xtG = bG + xk*wxG;
            const float xtO = bO + xk*wxO;
            // partial dots over this lane's 16 k's (4 parallel chains)
            v2f aI2, aF2, aG2, aO2;
            {
                const v2f p0 = (v2f){h4[0].x, h4[0].y};
                aI2 = wI[0]*p0; aF2 = wF[0]*p0; aG2 = wG[0]*p0; aO2 = wO[0]*p0;
            }
#pragma unroll
            for (int q = 1; q < 8; ++q) {
                const v4f hv = h4[q>>1];
                const v2f pp = (q&1) ? (v2f){hv.z, hv.w} : (v2f){hv.x, hv.y};
                aI2 += wI[q]*pp; aF2 += wF[q]*pp;
                aG2 += wG[q]*pp; aO2 += wO[q]*pp;
            }
            float aI = aI2.x + aI2.y, aF = aF2.x + aF2.y;
            float aG = aG2.x + aG2.y, aO = aO2.x + aO2.y;
            // combine k-halves across the lane pair (quad_perm [1,0,3,2])
            aI = dpp_add<0xB1,0xF,0xF,true>(aI, aI);
            aF = dpp_add<0xB1,0xF,0xF,true>(aF, aF);
            aG = dpp_add<0xB1,0xF,0xF,true>(aG, aG);
            aO = dpp_add<0xB1,0xF,0xF,true>(aO, aO);
            aI += xtI; aF += xtF; aG += xtG; aO += xtO;
            // transcendental split: this lane does P=(i|g), Q=(f|o)
            const float aP = odd ? aG : aI;
            const float aQ = odd ? aO : aF;
            const float actP = cP0 + cP1 * rcp_(1.0f + ex2_(aP));
            const float actQ = rcp_(1.0f + ex2_(aQ));
            const float nbP = dpp_movf<0xB1,0xF,0xF,true>(actP);
            const float nbQ = dpp_movf<0xB1,0xF,0xF,true>(actQ);
            const float iv = odd ? nbP : actP;
            const float fv = odd ? nbQ : actQ;
            const float gv = odd ? actP : nbP;
            const float ov = odd ? actQ : nbQ;
            c = fv*c + iv*gv;
            const float tc = 1.0f - 2.0f*rcp_(1.0f + ex2_((2.0f*L2E)*c));
            h = ov*tc;
            hbuf[wv][j] = h;          // pair writes same value (race-free)
            __asm__ __volatile__("" ::: "memory");
            // issue NEXT step's h reads now; projection below hides latency
#pragma unroll
            for (int q = 0; q < 4; ++q) h4[q] = ((const v4f*)hp)[q];
            // projection: full-wave DPP sum of h_j*W_out[j] (odd lanes 0)
            float pr = h * woutM;
            pr = dpp_add<0x111,0xF,0xF,true>(pr, pr);   // row_shr:1
            pr = dpp_add<0x112,0xF,0xF,true>(pr, pr);   // row_shr:2
            pr = dpp_add<0x114,0xF,0xF,true>(pr, pr);   // row_shr:4
            pr = dpp_add<0x118,0xF,0xF,true>(pr, pr);   // row_shr:8
            pr = dpp_add<0x142,0xA,0xF,false>(pr, pr);  // row_bcast:15
            const float s0 = __builtin_bit_cast(float,
                __builtin_amdgcn_readlane(__builtin_bit_cast(int, pr), 31));
            const float s1 = __builtin_bit_cast(float,
                __builtin_amdgcn_readlane(__builtin_bit_cast(int, pr), 63));
            if (l == 0) out[outOff] = s0 + s1 + bout;
            outOff += B_;
        }
        xcur = xnext;
    }
    // Final states: hT [1,B,H] then cT [1,B,H] (even lane of each pair)
    if (!odd) {
        out[OUTS + e*H_ + j] = h;
        out[OUTS + B_*H_ + e*H_ + j] = c;
    }
}

extern "C" void kernel_launch(void* const* d_in, const int* in_sizes, int n_in,
                              void* d_out, int out_size, void* d_ws, size_t ws_size,
                              hipStream_t stream) {
    const float* x     = (const float*)d_in[0];
    const float* W_ih  = (const float*)d_in[1];
    const float* W_hh  = (const float*)d_in[2];
    const float* b_ih  = (const float*)d_in[3];
    const float* b_hh  = (const float*)d_in[4];
    const float* W_out = (const float*)d_in[5];
    const float* b_out = (const float*)d_in[6];
    lstm_fused8<<<dim3(B_ / EPB), dim3(EPB * 64), 0, stream>>>(
        x, W_ih, W_hh, b_ih, b_hh, W_out, b_out, (float*)d_out);
}

// Round 9
// 792.464 us; speedup vs baseline: 1.0540x; 1.0540x over previous
//
#include <hip/hip_runtime.h>

// LSTM T=2048,B=2048,H=32,I=1,O=1 fused in ONE kernel.
// R9: R7's efficient shape (wave64 = 2 batch elements in lockstep halves;
// lane owns unit j = l&31 of its half's element, computes ALL 4 gates; f32
// throughout) but the LDS h-exchange -- R7's ~290 cyc/step stall -- is
// replaced by DPP gathers fused into the dot:
//   h_j lives in lane j's register. Weights are PRE-SKEWED per lane so at
//   rotation r lane j does acc += mov_dpp(h, row_ror:r) * w_skew[r].
//   row_ror covers the 16-lane row; the other 16 k's use one
//   ds_swizzle(h, xor16) (register permute, no LDS RAM), issued right after
//   h and consumed ~160 cyc later (latency hidden by same-row fmas).
// Recurrent chain = fma tree + activations only (~150 cyc) << issue, so
// wall ~= issue. 16 accumulators (4/gate) keep fma chains 8 deep.
// x broadcast via v_readlane; O=1 projection via DPP row_shr tree. Zero LDS.

namespace {
constexpr int T_ = 2048;
constexpr int B_ = 2048;
constexpr int H_ = 32;
constexpr int WPB = 4;              // waves per block; each wave = 2 elements
constexpr int EPB = WPB * 2;        // batch elements per block
constexpr int CHUNK = 32;           // timesteps of x held in one VGPR
constexpr int NCH = T_ / CHUNK;     // 64
constexpr int OUTS = T_ * B_;       // floats of outs [T,B,1]
constexpr float L2E = 1.442695040888963f;  // log2(e)

__device__ __forceinline__ float rcp_(float v){ return __builtin_amdgcn_rcpf(v); }
__device__ __forceinline__ float ex2_(float v){ return __builtin_amdgcn_exp2f(v); }

template <int CTRL, int RM, int BM, bool BC>
__device__ __forceinline__ float dpp_movf(float src) {
    return __builtin_bit_cast(float,
        __builtin_amdgcn_update_dpp(0, __builtin_bit_cast(int, src),
                                    CTRL, RM, BM, BC));
}
template <int CTRL, int RM, int BM, bool BC>
__device__ __forceinline__ float dpp_add(float acc, float src) {
    return acc + dpp_movf<CTRL,RM,BM,BC>(src);
}
// Sum within each 32-lane half; result in lane 31 (half0) / lane 63 (half1).
__device__ __forceinline__ float half_sum32(float v) {
    v = dpp_add<0x111,0xF,0xF,true >(v, v);  // row_shr:1
    v = dpp_add<0x112,0xF,0xF,true >(v, v);  // row_shr:2
    v = dpp_add<0x114,0xF,0xF,true >(v, v);  // row_shr:4
    v = dpp_add<0x118,0xF,0xF,true >(v, v);  // row_shr:8
    v = dpp_add<0x142,0xA,0xF,false>(v, v);  // row_bcast:15 -> rows 1,3
    return v;
}
} // namespace

__global__ __launch_bounds__(256, 1)
__attribute__((amdgpu_waves_per_eu(1, 1)))
void lstm_fused9(
    const float* __restrict__ x,      // [T,B,1]
    const float* __restrict__ W_ih,   // [4H,1]
    const float* __restrict__ W_hh,   // [4H,H]
    const float* __restrict__ b_ih,   // [4H]
    const float* __restrict__ b_hh,   // [4H]
    const float* __restrict__ W_out,  // [1,H]
    const float* __restrict__ b_out,  // [1]
    float* __restrict__ out)          // outs | hT | cT
{
    const int l  = threadIdx.x & 63;
    const int wv = threadIdx.x >> 6;
    const int j  = l & 31;            // hidden unit within element
    const int p  = l >> 5;            // element half within wave
    const int e  = blockIdx.x * EPB + wv * 2 + p;
    const int jl = l & 15;            // lane within 16-row
    const int rowoff   = j & 16;      // this row's unit offset (0 or 16)
    const int otheroff = 16 - rowoff; // other row's unit offset

    const float sI = -L2E, sF = -L2E, sG = 2.0f*L2E, sO = -L2E;

    // Pre-skewed weights: w?[r]      (r=0..15)  = W[gate][j][rowoff  +((jl-r)&15)]
    //                     w?[16+r]   (r=0..15)  = W[gate][j][otheroff+((jl-r)&15)]
    // so rotation r of h (row_ror:r) / of hs (swizzled rows) lines up.
    float wI[32], wF[32], wG[32], wO[32];
#pragma unroll
    for (int r = 0; r < 16; ++r) {
        const int ks = rowoff   + ((jl - r) & 15);
        const int kx = otheroff + ((jl - r) & 15);
        wI[r]    = W_hh[(0*H_+j)*H_ + ks] * sI;
        wI[16+r] = W_hh[(0*H_+j)*H_ + kx] * sI;
        wF[r]    = W_hh[(1*H_+j)*H_ + ks] * sF;
        wF[16+r] = W_hh[(1*H_+j)*H_ + kx] * sF;
        wG[r]    = W_hh[(2*H_+j)*H_ + ks] * sG;
        wG[16+r] = W_hh[(2*H_+j)*H_ + kx] * sG;
        wO[r]    = W_hh[(3*H_+j)*H_ + ks] * sO;
        wO[16+r] = W_hh[(3*H_+j)*H_ + kx] * sO;
    }
#pragma unroll
    for (int r = 0; r < 32; ++r) {   // keep VGPR-class
        __asm__ __volatile__("" : "+v"(wI[r]), "+v"(wF[r]));
        __asm__ __volatile__("" : "+v"(wG[r]), "+v"(wO[r]));
    }

    const float wxI = W_ih[0*H_+j]*sI, wxF = W_ih[1*H_+j]*sF;
    const float wxG = W_ih[2*H_+j]*sG, wxO = W_ih[3*H_+j]*sO;
    const float bI = (b_ih[0*H_+j]+b_hh[0*H_+j])*sI;
    const float bF = (b_ih[1*H_+j]+b_hh[1*H_+j])*sF;
    const float bG = (b_ih[2*H_+j]+b_hh[2*H_+j])*sG;
    const float bO = (b_ih[3*H_+j]+b_hh[3*H_+j])*sO;
    const float wout = W_out[j];
    const float bout = b_out[0];

    float c = 0.0f, h = 0.0f;
    float xcur = x[j * B_ + e];       // chunk 0: lane-of-half j holds t=j
    int outOff = e;                   // running offset: out[t*B_ + e]

    for (int ch = 0; ch < NCH; ++ch) {
        float xnext = 0.0f;
        if (ch + 1 < NCH) xnext = x[((ch+1)*CHUNK + j) * B_ + e];
#pragma unroll 4
        for (int s = 0; s < CHUNK; ++s) {
            // cross-row copy of h (row swap within each 32-lane half);
            // register permute, no LDS RAM; consumed ~160 cyc later.
            const float hs = __builtin_bit_cast(float,
                __builtin_amdgcn_ds_swizzle(__builtin_bit_cast(int, h), 0x401F));
            // x broadcast (uniform lane index per half)
            const int xr0 = __builtin_amdgcn_readlane(__builtin_bit_cast(int, xcur), s);
            const int xr1 = __builtin_amdgcn_readlane(__builtin_bit_cast(int, xcur), s + 32);
            const float xk = p ? __builtin_bit_cast(float, xr1)
                               : __builtin_bit_cast(float, xr0);
            // 4 accumulators per gate; acc0 starts at the x-term
            float aI0 = bI + xk*wxI, aI1 = 0.f, aI2 = 0.f, aI3 = 0.f;
            float aF0 = bF + xk*wxF, aF1 = 0.f, aF2 = 0.f, aF3 = 0.f;
            float aG0 = bG + xk*wxG, aG1 = 0.f, aG2 = 0.f, aG3 = 0.f;
            float aO0 = bO + xk*wxO, aO1 = 0.f, aO2 = 0.f, aO3 = 0.f;
            // r = 0: h directly
            aI0 += wI[0]*h; aF0 += wF[0]*h; aG0 += wG[0]*h; aO0 += wO[0]*h;
#define ROR_STEP(R, IDX)                                                     \
            { const float hr_ = dpp_movf<0x120+(R),0xF,0xF,true>(h);         \
              aI##IDX += wI[R]*hr_; aF##IDX += wF[R]*hr_;                    \
              aG##IDX += wG[R]*hr_; aO##IDX += wO[R]*hr_; }
            ROR_STEP(1,1)  ROR_STEP(2,2)  ROR_STEP(3,3)
            ROR_STEP(4,0)  ROR_STEP(5,1)  ROR_STEP(6,2)  ROR_STEP(7,3)
            ROR_STEP(8,0)  ROR_STEP(9,1)  ROR_STEP(10,2) ROR_STEP(11,3)
            ROR_STEP(12,0) ROR_STEP(13,1) ROR_STEP(14,2) ROR_STEP(15,3)
#undef ROR_STEP
            // cross-row half: same rotations on hs
            aI0 += wI[16]*hs; aF0 += wF[16]*hs; aG0 += wG[16]*hs; aO0 += wO[16]*hs;
#define RORX_STEP(R, IDX)                                                    \
            { const float hr_ = dpp_movf<0x120+(R),0xF,0xF,true>(hs);        \
              aI##IDX += wI[16+(R)]*hr_; aF##IDX += wF[16+(R)]*hr_;          \
              aG##IDX += wG[16+(R)]*hr_; aO##IDX += wO[16+(R)]*hr_; }
            RORX_STEP(1,1)  RORX_STEP(2,2)  RORX_STEP(3,3)
            RORX_STEP(4,0)  RORX_STEP(5,1)  RORX_STEP(6,2)  RORX_STEP(7,3)
            RORX_STEP(8,0)  RORX_STEP(9,1)  RORX_STEP(10,2) RORX_STEP(11,3)
            RORX_STEP(12,0) RORX_STEP(13,1) RORX_STEP(14,2) RORX_STEP(15,3)
#undef RORX_STEP
            const float aI = (aI0+aI1)+(aI2+aI3);
            const float aF = (aF0+aF1)+(aF2+aF3);
            const float aG = (aG0+aG1)+(aG2+aG3);
            const float aO = (aO0+aO1)+(aO2+aO3);
            const float iv = rcp_(1.0f + ex2_(aI));
            const float fv = rcp_(1.0f + ex2_(aF));
            const float gv = 1.0f - 2.0f*rcp_(1.0f + ex2_(aG));
            const float ov = rcp_(1.0f + ex2_(aO));
            c = fv*c + iv*gv;
            const float tc = 1.0f - 2.0f*rcp_(1.0f + ex2_((2.0f*L2E)*c));
            h = ov*tc;                 // stays in-register; no publish needed
            // output projection: DPP half-sum (pure VALU)
            const float pr = half_sum32(h * wout);
            if ((l & 31) == 31) out[outOff] = pr + bout;
            outOff += B_;
        }
        xcur = xnext;
    }
    // Final states: hT [1,B,H] then cT [1,B,H] — valid on every lane.
    out[OUTS + e*H_ + j] = h;
    out[OUTS + B_*H_ + e*H_ + j] = c;
}

extern "C" void kernel_launch(void* const* d_in, const int* in_sizes, int n_in,
                              void* d_out, int out_size, void* d_ws, size_t ws_size,
                              hipStream_t stream) {
    const float* x     = (const float*)d_in[0];
    const float* W_ih  = (const float*)d_in[1];
    const float* W_hh  = (const float*)d_in[2];
    const float* b_ih  = (const float*)d_in[3];
    const float* b_hh  = (const float*)d_in[4];
    const float* W_out = (const float*)d_in[5];
    const float* b_out = (const float*)d_in[6];
    lstm_fused9<<<dim3(B_ / EPB), dim3(256), 0, stream>>>(
        x, W_ih, W_hh, b_ih, b_hh, W_out, b_out, (float*)d_out);
}

// Round 10
// 712.395 us; speedup vs baseline: 1.1725x; 1.1124x over previous
//
#include <hip/hip_runtime.h>

// LSTM T=2048,B=2048,H=32,I=1,O=1 fused in ONE kernel.
// R10 = R7 (best: 723us) with ONE change under test:
//   __attribute__((amdgpu_num_vgpr(256))) -- explicit VGPR budget.
// Diagnosis: R4/R7/R9 all report VGPR_Count=100 (R8: 56) while the declared
// register working set is ~160-190 (128 f32 weights + accums + state). The
// allocator consistently parks the surplus in AGPRs (gfx950 unified file)
// and issues v_accvgpr_read copies every use -- the persistent ~120-190
// cyc/step gap between source instruction count and measured VALU issue.
// waves_per_eu and asm pins never moved the cap; num_vgpr is a direct
// budget request. In-loop pins removed (suspected copy generators);
// init-time pins kept.
// Shape (R7): wave64 = 2 batch elements in lockstep halves; lane owns unit
// j=l&31 of its half's element, computes all 4 gates; f32 throughout;
// LDS h broadcast; DPP O=1 projection; v_readlane x broadcast.

namespace {
constexpr int T_ = 2048;
constexpr int B_ = 2048;
constexpr int H_ = 32;
constexpr int WPB = 4;              // waves per block; each wave = 2 elements
constexpr int EPB = WPB * 2;        // batch elements per block
constexpr int CHUNK = 32;           // timesteps of x held in one VGPR
constexpr int NCH = T_ / CHUNK;     // 64
constexpr int OUTS = T_ * B_;       // floats of outs [T,B,1]
constexpr float L2E = 1.442695040888963f;  // log2(e)

typedef float v2f __attribute__((ext_vector_type(2)));
typedef float v4f __attribute__((ext_vector_type(4)));

__device__ __forceinline__ float rcp_(float v){ return __builtin_amdgcn_rcpf(v); }
__device__ __forceinline__ float ex2_(float v){ return __builtin_amdgcn_exp2f(v); }

template <int CTRL, int RM, int BM, bool BC>
__device__ __forceinline__ float dpp_add(float acc, float src) {
    int mv = __builtin_amdgcn_update_dpp(0, __builtin_bit_cast(int, src),
                                         CTRL, RM, BM, BC);
    return acc + __builtin_bit_cast(float, mv);
}
// Sum within each 32-lane half; result in lane 31 (half0) / lane 63 (half1).
__device__ __forceinline__ float half_sum32(float v) {
    v = dpp_add<0x111, 0xF, 0xF, true >(v, v);  // row_shr:1
    v = dpp_add<0x112, 0xF, 0xF, true >(v, v);  // row_shr:2
    v = dpp_add<0x114, 0xF, 0xF, true >(v, v);  // row_shr:4
    v = dpp_add<0x118, 0xF, 0xF, true >(v, v);  // row_shr:8
    v = dpp_add<0x142, 0xA, 0xF, false>(v, v);  // row_bcast:15 -> rows 1,3
    return v;
}
} // namespace

__global__ __launch_bounds__(256, 1)
__attribute__((amdgpu_num_vgpr(256)))
void lstm_fused10(
    const float* __restrict__ x,      // [T,B,1]
    const float* __restrict__ W_ih,   // [4H,1]
    const float* __restrict__ W_hh,   // [4H,H]
    const float* __restrict__ b_ih,   // [4H]
    const float* __restrict__ b_hh,   // [4H]
    const float* __restrict__ W_out,  // [1,H]
    const float* __restrict__ b_out,  // [1]
    float* __restrict__ out)          // outs | hT | cT
{
    const int l  = threadIdx.x & 63;
    const int wv = threadIdx.x >> 6;
    const int j  = l & 31;            // hidden unit
    const int p  = l >> 5;            // element half within wave
    const int e  = blockIdx.x * EPB + wv * 2 + p;

    __shared__ __align__(16) float hbuf[WPB][2][H_];

    const float sI = -L2E, sF = -L2E, sG = 2.0f * L2E, sO = -L2E;

    // W_hh rows j (i), j+H (f), j+2H (g), j+3H (o); packed k-pairs, pre-scaled
    // so activations need no dependent mul before exp2.
    v2f wi[H_/2], wf[H_/2], wg[H_/2], wo[H_/2];
#pragma unroll
    for (int k2 = 0; k2 < H_/2; ++k2) {
        const float* ri = W_hh + (0*H_ + j) * H_;
        const float* rf = W_hh + (1*H_ + j) * H_;
        const float* rg = W_hh + (2*H_ + j) * H_;
        const float* ro = W_hh + (3*H_ + j) * H_;
        wi[k2] = (v2f){ ri[2*k2] * sI, ri[2*k2+1] * sI };
        wf[k2] = (v2f){ rf[2*k2] * sF, rf[2*k2+1] * sF };
        wg[k2] = (v2f){ rg[2*k2] * sG, rg[2*k2+1] * sG };
        wo[k2] = (v2f){ ro[2*k2] * sO, ro[2*k2+1] * sO };
    }
    // Init-time pins only (in-loop pins suspected of generating copies).
#pragma unroll
    for (int k2 = 0; k2 < H_/2; ++k2) {
        __asm__ __volatile__("" : "+v"(wi[k2]));
        __asm__ __volatile__("" : "+v"(wf[k2]));
        __asm__ __volatile__("" : "+v"(wg[k2]));
        __asm__ __volatile__("" : "+v"(wo[k2]));
    }

    const float wxi = W_ih[0*H_+j] * sI, wxf = W_ih[1*H_+j] * sF;
    const float wxg = W_ih[2*H_+j] * sG, wxo = W_ih[3*H_+j] * sO;
    const float bi  = (b_ih[0*H_+j] + b_hh[0*H_+j]) * sI;
    const float bf  = (b_ih[1*H_+j] + b_hh[1*H_+j]) * sF;
    const float bg  = (b_ih[2*H_+j] + b_hh[2*H_+j]) * sG;
    const float bo_ = (b_ih[3*H_+j] + b_hh[3*H_+j]) * sO;
    const float wout = W_out[j];
    const float bout = b_out[0];

    float c = 0.0f, h = 0.0f;
    hbuf[wv][p][j] = 0.0f;               // h0 = 0
    __asm__ __volatile__("" ::: "memory");
    v4f hq[H_/4];
#pragma unroll
    for (int q = 0; q < H_/4; ++q)       // h_0 fragments for step 0
        hq[q] = ((const v4f*)&hbuf[wv][p][0])[q];

    float xcur = x[j * B_ + e];          // chunk 0: lane j holds t=j
    int outOff = e;                      // running offset: out[t*B_+e]

    for (int ch = 0; ch < NCH; ++ch) {
        float xnext = 0.0f;
        if (ch + 1 < NCH) xnext = x[((ch + 1) * CHUNK + j) * B_ + e];
#pragma unroll 8
        for (int s = 0; s < CHUNK; ++s) {
            // x broadcast: register readlane (h-independent, off the chain)
            const int xr0 = __builtin_amdgcn_readlane(__builtin_bit_cast(int, xcur), s);
            const int xr1 = __builtin_amdgcn_readlane(__builtin_bit_cast(int, xcur), s + 32);
            const float xk = p ? __builtin_bit_cast(float, xr1)
                               : __builtin_bit_cast(float, xr0);
            // dot accumulators start at the x-term (saves the merge adds)
            v2f ai0 = {bi  + xk * wxi, 0.f}, ai1 = {0.f, 0.f};
            v2f af0 = {bf  + xk * wxf, 0.f}, af1 = {0.f, 0.f};
            v2f ag0 = {bg  + xk * wxg, 0.f}, ag1 = {0.f, 0.f};
            v2f ao0 = {bo_ + xk * wxo, 0.f}, ao1 = {0.f, 0.f};
#pragma unroll
            for (int q = 0; q < H_/4; ++q) {
                const v2f hlo = (v2f){ hq[q].x, hq[q].y };
                const v2f hhi = (v2f){ hq[q].z, hq[q].w };
                ai0 += wi[2*q] * hlo;  ai1 += wi[2*q+1] * hhi;
                af0 += wf[2*q] * hlo;  af1 += wf[2*q+1] * hhi;
                ag0 += wg[2*q] * hlo;  ag1 += wg[2*q+1] * hhi;
                ao0 += wo[2*q] * hlo;  ao1 += wo[2*q+1] * hhi;
            }
            const v2f ai = ai0 + ai1, af = af0 + af1;
            const v2f ag = ag0 + ag1, ao = ao0 + ao1;
            const float iv = rcp_(1.0f + ex2_(ai.x + ai.y));
            const float fv = rcp_(1.0f + ex2_(af.x + af.y));
            const float gv = 1.0f - 2.0f * rcp_(1.0f + ex2_(ag.x + ag.y));
            const float ov = rcp_(1.0f + ex2_(ao.x + ao.y));
            c = fv * c + iv * gv;
            const float tc = 1.0f - 2.0f * rcp_(1.0f + ex2_((2.0f * L2E) * c));
            h = ov * tc;
            hbuf[wv][p][j] = h;           // publish h_t
            __asm__ __volatile__("" ::: "memory");
            // issue NEXT step's h reads immediately; work below hides latency
#pragma unroll
            for (int q = 0; q < H_/4; ++q)
                hq[q] = ((const v4f*)&hbuf[wv][p][0])[q];
            // output projection: DPP half-sum (pure VALU, no lgkm waits)
            const float pr = half_sum32(h * wout);
            if ((l & 31) == 31) out[outOff] = pr + bout;
            outOff += B_;
        }
        xcur = xnext;
    }
    // Final states: hT [1,B,H] then cT [1,B,H] — valid on every lane.
    out[OUTS + e * H_ + j] = h;
    out[OUTS + B_ * H_ + e * H_ + j] = c;
}

extern "C" void kernel_launch(void* const* d_in, const int* in_sizes, int n_in,
                              void* d_out, int out_size, void* d_ws, size_t ws_size,
                              hipStream_t stream) {
    const float* x     = (const float*)d_in[0];
    const float* W_ih  = (const float*)d_in[1];
    const float* W_hh  = (const float*)d_in[2];
    const float* b_ih  = (const float*)d_in[3];
    const float* b_hh  = (const float*)d_in[4];
    const float* W_out = (const float*)d_in[5];
    const float* b_out = (const float*)d_in[6];
    lstm_fused10<<<dim3(B_ / EPB), dim3(256), 0, stream>>>(
        x, W_ih, W_hh, b_ih, b_hh, W_out, b_out, (float*)d_out);
}